// Round 1
// baseline (172.859 us; speedup 1.0000x reference)
//
#include <hip/hip_runtime.h>
#include <hip/hip_bf16.h>
#include <stdint.h>

// SimCLR loss, N=16384 rows, D=128, T=0.07.
// Strategy: bf16 MFMA flash-style fused row-max + online exp2-sum over the
// 16384x16384 similarity matrix; diagonal masked; positive-pair dots in f32.
// Features pre-scaled by sqrt(log2e/T) so MFMA emits base-2 logits directly.

#define B_HALF 8192
#define N_TOT 16384
#define DIM 128
#define SPLITS 8
#define BM 256                      // rows per workgroup (4 waves x 64 rows)
#define BN 64                       // column tile
#define COLS_PER_WG (N_TOT / SPLITS)   // 2048
#define N_TILES (COLS_PER_WG / BN)     // 32

typedef __attribute__((ext_vector_type(8))) short short8;   // 8 x bf16 (4 VGPR)
typedef __attribute__((ext_vector_type(4))) float f32x4;

static constexpr float SCALE_IN = 4.5398160f;   // sqrt(log2(e)/0.07)
static constexpr float LN2_F    = 0.69314718056f;
static constexpr float INV_T    = 14.2857142857f;

__device__ __forceinline__ unsigned short f2bf_rne(float x) {
  unsigned int u = __float_as_uint(x);
  u += 0x7fffu + ((u >> 16) & 1u);
  return (unsigned short)(u >> 16);
}

// ---------------- convert: f32 -> pre-scaled bf16 ----------------
__global__ void k_convert(const float* __restrict__ orig,
                          const float* __restrict__ aug,
                          unsigned short* __restrict__ feats) {
  int idx = blockIdx.x * blockDim.x + threadIdx.x;
  const int total4 = N_TOT * DIM / 4;
  if (idx >= total4) return;
  int e = idx * 4;
  const int half_e = B_HALF * DIM;
  const float4 v = (e < half_e) ? *(const float4*)(orig + e)
                                : *(const float4*)(aug + (e - half_e));
  ushort4 r;
  r.x = f2bf_rne(v.x * SCALE_IN);
  r.y = f2bf_rne(v.y * SCALE_IN);
  r.z = f2bf_rne(v.z * SCALE_IN);
  r.w = f2bf_rne(v.w * SCALE_IN);
  *(ushort4*)(feats + e) = r;
}

// ---------------- positive-pair dots (exact f32) ----------------
__global__ void k_pos(const float* __restrict__ orig,
                      const float* __restrict__ aug,
                      float* __restrict__ pos) {
  int gtid = blockIdx.x * blockDim.x + threadIdx.x;
  int wid = gtid >> 6;
  int lane = threadIdx.x & 63;
  int nwaves = (gridDim.x * blockDim.x) >> 6;
  for (int row = wid; row < B_HALF; row += nwaves) {
    const float2 a = *(const float2*)(orig + row * DIM + lane * 2);
    const float2 b = *(const float2*)(aug  + row * DIM + lane * 2);
    float d = a.x * b.x + a.y * b.y;
    #pragma unroll
    for (int off = 32; off > 0; off >>= 1) d += __shfl_down(d, off);
    if (lane == 0) pos[row] = d * INV_T;
  }
}

// ---------------- per-tile online softmax update ----------------
template <bool MASKED>
__device__ __forceinline__ void tile_softmax_update(
    const f32x4 acc[4][4], int tb, int Rw, int c4, int q,
    float* m_, float* l_) {
  #pragma unroll
  for (int g2 = 0; g2 < 4; ++g2) {
    #pragma unroll
    for (int r = 0; r < 4; ++r) {
      float v0 = acc[g2][0][r];
      float v1 = acc[g2][1][r];
      float v2 = acc[g2][2][r];
      float v3 = acc[g2][3][r];
      if (MASKED) {
        // C/D layout (verified m89/m91): col = lane&15, row = quad*4 + reg
        int row = Rw + g2 * 16 + q * 4 + r;
        int cb = tb + c4;
        if (cb      == row) v0 = -1e30f;
        if (cb + 16 == row) v1 = -1e30f;
        if (cb + 32 == row) v2 = -1e30f;
        if (cb + 48 == row) v3 = -1e30f;
      }
      float rmax = fmaxf(fmaxf(v0, v1), fmaxf(v2, v3));
      int idx = g2 * 4 + r;
      float mo = m_[idx];
      float mn = fmaxf(mo, rmax);
      float alpha = __builtin_amdgcn_exp2f(mo - mn);
      float s = __builtin_amdgcn_exp2f(v0 - mn) + __builtin_amdgcn_exp2f(v1 - mn)
              + __builtin_amdgcn_exp2f(v2 - mn) + __builtin_amdgcn_exp2f(v3 - mn);
      l_[idx] = l_[idx] * alpha + s;
      m_[idx] = mn;
    }
  }
}

// ---------------- main fused kernel ----------------
__global__ __launch_bounds__(256, 2)
void k_main(const unsigned short* __restrict__ feats,
            float* __restrict__ pm, float* __restrict__ pl) {
  __shared__ __align__(16) char lds[2][BN * DIM * 2];  // 2 x 16 KiB

  const int tid = threadIdx.x;
  const int wave = tid >> 6;
  const int lane = tid & 63;
  const int q = lane >> 4;
  const int c4 = lane & 15;

  const int rowblk = blockIdx.x >> 3;          // 64 row blocks
  const int split = blockIdx.x & (SPLITS - 1); // 8 column splits
  const int R0 = rowblk * BM;
  const int Rw = R0 + wave * 64;               // this wave's 64 rows
  const int col0 = split * COLS_PER_WG;

  // A fragments for 64 rows x K=128, kept in registers for the whole scan.
  // A layout (16x16x32): m = lane&15, k = quad*8 + j  (j contiguous)
  short8 af[4][4];
  #pragma unroll
  for (int g = 0; g < 4; ++g)
    #pragma unroll
    for (int s = 0; s < 4; ++s)
      af[g][s] = *(const short8*)(feats + (size_t)(Rw + g * 16 + c4) * DIM + s * 32 + q * 8);

  float m_[16], l_[16];
  #pragma unroll
  for (int i = 0; i < 16; ++i) { m_[i] = -1e30f; l_[i] = 0.0f; }

  // Staging: tile = 64 cols x 16 granules(16B). LDS granule L = 16*c + (g ^ (c&7))
  // (XOR swizzle -> conflict-free ds_read_b128 despite wave-uniform-base DMA).
  const unsigned short* gsrc[4];
  #pragma unroll
  for (int t = 0; t < 4; ++t) {
    int Lg = (wave * 4 + t) * 64 + lane;
    int c = Lg >> 4;
    int g = (Lg & 15) ^ (c & 7);
    gsrc[t] = feats + (size_t)(col0 + c) * DIM + g * 8;
  }

  // prologue: stage tile 0 into buf 0
  #pragma unroll
  for (int t = 0; t < 4; ++t) {
    __builtin_amdgcn_global_load_lds(
        (const __attribute__((address_space(1))) unsigned int*)(gsrc[t]),
        (__attribute__((address_space(3))) unsigned int*)(&lds[0][(wave * 4 + t) * 1024]),
        16, 0, 0);
  }

  const f32x4 zero = {0.0f, 0.0f, 0.0f, 0.0f};

  for (int tile = 0; tile < N_TILES; ++tile) {
    __syncthreads();  // drains global_load_lds (vmcnt0) + protects buf reuse
    int buf = tile & 1;
    if (tile + 1 < N_TILES) {
      #pragma unroll
      for (int t = 0; t < 4; ++t) {
        __builtin_amdgcn_global_load_lds(
            (const __attribute__((address_space(1))) unsigned int*)(gsrc[t] + (size_t)(tile + 1) * BN * DIM),
            (__attribute__((address_space(3))) unsigned int*)(&lds[buf ^ 1][(wave * 4 + t) * 1024]),
            16, 0, 0);
      }
    }

    const char* Lb = lds[buf];
    f32x4 acc[4][4];
    #pragma unroll
    for (int s = 0; s < 4; ++s) {
      short8 bf[4];
      #pragma unroll
      for (int u = 0; u < 4; ++u) {
        // B layout mirrors A: n = lane&15, k = quad*8 + j ; granule g = 4s+q
        int c = u * 16 + c4;
        int g = s * 4 + q;
        int off = c * 256 + ((g ^ (c & 7)) * 16);
        bf[u] = *(const short8*)(Lb + off);
      }
      #pragma unroll
      for (int g2 = 0; g2 < 4; ++g2) {
        #pragma unroll
        for (int u = 0; u < 4; ++u) {
          if (s == 0)
            acc[g2][u] = __builtin_amdgcn_mfma_f32_16x16x32_bf16(af[g2][0], bf[u], zero, 0, 0, 0);
          else
            acc[g2][u] = __builtin_amdgcn_mfma_f32_16x16x32_bf16(af[g2][s], bf[u], acc[g2][u], 0, 0, 0);
        }
      }
    }

    int tb = col0 + tile * BN;
    bool masked = (tb + BN > R0) && (tb < R0 + BM);  // wave-uniform
    if (masked) tile_softmax_update<true >(acc, tb, Rw, c4, q, m_, l_);
    else        tile_softmax_update<false>(acc, tb, Rw, c4, q, m_, l_);
  }

  // combine (m,l) across the 16 column-lanes of each quad, write partials
  #pragma unroll
  for (int idx = 0; idx < 16; ++idx) {
    float mm = m_[idx], ll = l_[idx];
    #pragma unroll
    for (int d = 1; d < 16; d <<= 1) {
      float mo = __shfl_xor(mm, d);
      float lo = __shfl_xor(ll, d);
      float mn = fmaxf(mm, mo);
      ll = ll * __builtin_amdgcn_exp2f(mm - mn) + lo * __builtin_amdgcn_exp2f(mo - mn);
      mm = mn;
    }
    if (c4 == 0) {
      int row = Rw + (idx >> 2) * 16 + q * 4 + (idx & 3);
      pm[split * N_TOT + row] = mm;
      pl[split * N_TOT + row] = ll;
    }
  }
}

// ---------------- final combine + mean ----------------
__global__ void k_reduce(const float* __restrict__ pm, const float* __restrict__ pl,
                         const float* __restrict__ pos, float* __restrict__ out) {
  int i = blockIdx.x * blockDim.x + threadIdx.x;  // one thread per row
  float mm = -1e30f, ll = 0.0f;
  #pragma unroll
  for (int s = 0; s < SPLITS; ++s) {
    float mo = pm[s * N_TOT + i];
    float lo = pl[s * N_TOT + i];
    float mn = fmaxf(mm, mo);
    ll = ll * __builtin_amdgcn_exp2f(mm - mn) + lo * __builtin_amdgcn_exp2f(mo - mn);
    mm = mn;
  }
  float lse = LN2_F * (mm + __builtin_amdgcn_logf(ll));   // natural-log lse
  float term = lse - pos[i & (B_HALF - 1)];

  int lane = threadIdx.x & 63;
  int wv = threadIdx.x >> 6;
  #pragma unroll
  for (int off = 32; off > 0; off >>= 1) term += __shfl_down(term, off);
  __shared__ float red[4];
  if (lane == 0) red[wv] = term;
  __syncthreads();
  if (threadIdx.x == 0) {
    float s = red[0] + red[1] + red[2] + red[3];
    atomicAdd(out, s * (1.0f / N_TOT));
  }
}

extern "C" void kernel_launch(void* const* d_in, const int* in_sizes, int n_in,
                              void* d_out, int out_size, void* d_ws, size_t ws_size,
                              hipStream_t stream) {
  const float* orig = (const float*)d_in[0];
  const float* aug  = (const float*)d_in[1];
  float* out = (float*)d_out;

  // workspace layout (needs ~5.03 MiB):
  char* ws = (char*)d_ws;
  unsigned short* feats = (unsigned short*)(ws);                       // 4 MiB bf16 [N][D]
  float* pm  = (float*)(ws + (size_t)4 * 1024 * 1024);                 // 512 KiB
  float* pl  = (float*)(ws + (size_t)4 * 1024 * 1024 + 512 * 1024);    // 512 KiB
  float* pos = (float*)(ws + (size_t)5 * 1024 * 1024);                 // 32 KiB

  hipMemsetAsync(d_out, 0, sizeof(float), stream);
  k_convert<<<(N_TOT * DIM / 4 + 255) / 256, 256, 0, stream>>>(orig, aug, feats);
  k_pos<<<128, 256, 0, stream>>>(orig, aug, pos);
  k_main<<<(N_TOT / BM) * SPLITS, 256, 0, stream>>>(feats, pm, pl);
  k_reduce<<<N_TOT / 256, 256, 0, stream>>>(pm, pl, pos, out);
}